// Round 3
// baseline (1103.847 us; speedup 1.0000x reference)
//
#include <hip/hip_runtime.h>

#define TLEN  1024
#define HN    64
#define LOG2E 1.4426950408889634f

// One wave (64 threads) per batch element. Lane g owns hidden unit g: all
// four gate rows (torch order i,f,g,o => rows g, 64+g, 128+g, 192+g) pinned
// in 256 VGPRs. __launch_bounds__(64,1) lifts the VGPR cap to 512 (the
// R1/R2 failure: (256,4) capped at 128 -> compiler rematerialized/spilled
// the weight array -> L2-reload-bound at ~1 ms).
// h-broadcast via v_readlane (no LDS, no barrier in the recurrence).
// exp2-based activations with log2e pre-folded into weights/biases.
// FC output: per-step partial -> LDS ring [64 t][68 pad], transposed
// tree-reduction + coalesced store every 64 steps.
__global__ __launch_bounds__(64, 1)
void lstm_fused(const float* __restrict__ x,      // [B, T, 4]
                const float* __restrict__ W_ih,   // [256, 4]
                const float* __restrict__ W_hh,   // [256, 64]
                const float* __restrict__ b_ih,   // [256]
                const float* __restrict__ b_hh,   // [256]
                const float* __restrict__ W_fc,   // [1, 64]
                const float* __restrict__ b_fc,   // [1]
                float* __restrict__ out)          // [B, T]
{
    const int b = blockIdx.x;
    const int g = threadIdx.x;   // hidden unit 0..63

    __shared__ __align__(16) float p_s[64][68];   // FC partials ring (padded)

    // ---- one-time: load + pre-scale this lane's 4 weight rows ----
    // rows: i=g, f=64+g, g=128+g, o=192+g. Sigmoid rows scaled by log2e,
    // tanh (g) row by 2*log2e, so activations use raw exp2.
    float4 w4[HN];   // w4[j] = {wi[j], wf[j], wg[j], wo[j]} pre-scaled
#pragma unroll
    for (int j = 0; j < HN; ++j) {
        w4[j].x = W_hh[(0 * HN + g) * HN + j] * LOG2E;
        w4[j].y = W_hh[(1 * HN + g) * HN + j] * LOG2E;
        w4[j].z = W_hh[(2 * HN + g) * HN + j] * (2.0f * LOG2E);
        w4[j].w = W_hh[(3 * HN + g) * HN + j] * LOG2E;
    }
    float4 wih_i = *(const float4*)(W_ih + (0 * HN + g) * 4);
    float4 wih_f = *(const float4*)(W_ih + (1 * HN + g) * 4);
    float4 wih_g = *(const float4*)(W_ih + (2 * HN + g) * 4);
    float4 wih_o = *(const float4*)(W_ih + (3 * HN + g) * 4);
    wih_i.x *= LOG2E; wih_i.y *= LOG2E; wih_i.z *= LOG2E; wih_i.w *= LOG2E;
    wih_f.x *= LOG2E; wih_f.y *= LOG2E; wih_f.z *= LOG2E; wih_f.w *= LOG2E;
    wih_g.x *= 2.0f * LOG2E; wih_g.y *= 2.0f * LOG2E;
    wih_g.z *= 2.0f * LOG2E; wih_g.w *= 2.0f * LOG2E;
    wih_o.x *= LOG2E; wih_o.y *= LOG2E; wih_o.z *= LOG2E; wih_o.w *= LOG2E;

    const float bias_i = (b_ih[0 * HN + g] + b_hh[0 * HN + g]) * LOG2E;
    const float bias_f = (b_ih[1 * HN + g] + b_hh[1 * HN + g]) * LOG2E;
    const float bias_g = (b_ih[2 * HN + g] + b_hh[2 * HN + g]) * (2.0f * LOG2E);
    const float bias_o = (b_ih[3 * HN + g] + b_hh[3 * HN + g]) * LOG2E;
    const float wfc = W_fc[g];
    const float bfc = b_fc[0];

    const float* xb = x   + (size_t)b * TLEN * 4;
    float*       ob = out + (size_t)b * TLEN;

    float h = 0.0f, c = 0.0f;
    float4 xt = *(const float4*)(xb);   // software-pipelined x load

    for (int t = 0; t < TLEN; ++t) {
        int tn = t + 1; if (tn >= TLEN) tn = TLEN - 1;
        float4 xnext = *(const float4*)(xb + (size_t)tn * 4);

        // ---- gate pre-activations (pre-scaled units) ----
        float ai = bias_i + wih_i.x * xt.x + wih_i.y * xt.y
                          + wih_i.z * xt.z + wih_i.w * xt.w;
        float af = bias_f + wih_f.x * xt.x + wih_f.y * xt.y
                          + wih_f.z * xt.z + wih_f.w * xt.w;
        float ag = bias_g + wih_g.x * xt.x + wih_g.y * xt.y
                          + wih_g.z * xt.z + wih_g.w * xt.w;
        float ao = bias_o + wih_o.x * xt.x + wih_o.y * xt.y
                          + wih_o.z * xt.z + wih_o.w * xt.w;

        // matvec: h broadcast lane-by-lane via readlane -> SGPR (1:4 ratio)
#pragma unroll
        for (int j = 0; j < HN; ++j) {
            float hj = __int_as_float(
                __builtin_amdgcn_readlane(__float_as_int(h), j));
            ai += w4[j].x * hj;
            af += w4[j].y * hj;
            ag += w4[j].z * hj;
            ao += w4[j].w * hj;
        }

        // ---- activations: sigmoid(a) = rcp(1+2^-a'), tanh = 1-2*rcp(1+2^a'')
        float si = __builtin_amdgcn_rcpf(1.0f + __builtin_amdgcn_exp2f(-ai));
        float sf = __builtin_amdgcn_rcpf(1.0f + __builtin_amdgcn_exp2f(-af));
        float tg = 1.0f - 2.0f * __builtin_amdgcn_rcpf(
                                     1.0f + __builtin_amdgcn_exp2f(ag));
        float so = __builtin_amdgcn_rcpf(1.0f + __builtin_amdgcn_exp2f(-ao));

        c = sf * c + si * tg;
        float th = 1.0f - 2.0f * __builtin_amdgcn_rcpf(
                       1.0f + __builtin_amdgcn_exp2f(c * (2.0f * LOG2E)));
        h = so * th;

        // FC partial into ring; reduce+store every 64 steps
        p_s[t & 63][g] = h * wfc;
        if ((t & 63) == 63) {
            __syncthreads();   // single wave: cheap; orders LDS writes/reads
            const float4* pr = (const float4*)&p_s[g][0];
            float s0 = 0.f, s1 = 0.f, s2 = 0.f, s3 = 0.f;
#pragma unroll
            for (int k = 0; k < 16; ++k) {
                float4 v = pr[k];
                s0 += v.x; s1 += v.y; s2 += v.z; s3 += v.w;
            }
            ob[(t - 63) + g] = (s0 + s1) + (s2 + s3) + bfc;
        }
        xt = xnext;
    }
}

extern "C" void kernel_launch(void* const* d_in, const int* in_sizes, int n_in,
                              void* d_out, int out_size, void* d_ws, size_t ws_size,
                              hipStream_t stream) {
    const float* x    = (const float*)d_in[0];
    const float* W_ih = (const float*)d_in[1];
    const float* W_hh = (const float*)d_in[2];
    const float* b_ih = (const float*)d_in[3];
    const float* b_hh = (const float*)d_in[4];
    const float* W_fc = (const float*)d_in[5];
    const float* b_fc = (const float*)d_in[6];
    float* out = (float*)d_out;

    const int B = in_sizes[0] / (TLEN * 4);   // 1024
    lstm_fused<<<dim3(B), dim3(64), 0, stream>>>(
        x, W_ih, W_hh, b_ih, b_hh, W_fc, b_fc, out);
}

// Round 4
// 977.022 us; speedup vs baseline: 1.1298x; 1.1298x over previous
//
#include <hip/hip_runtime.h>

#define TLEN  1024
#define HN    64
#define LOG2E 1.4426950408889634f

// One wave (64 lanes) per batch element. Lane g owns hidden unit g: all four
// gate rows (torch i,f,g,o = rows g, 64+g, 128+g, 192+g) held in 256
// INDIVIDUALLY-NAMED floats -- R3's float4 w4[64] alloca was sent to scratch
// by promote-alloca (VGPR=152, 42ms scratch-touch dispatch); named scalars
// cannot be demoted. __launch_bounds__(64,1) -> 512-VGPR budget.
// h broadcast lane-by-lane via v_readlane -> SGPR operand of v_fma (1:4).
// exp2-based activations with log2e pre-folded into weights/biases.
// FC: per-step h*wfc -> LDS ring [64][65] (stride-65 = conflict-free scalar
// reads), transposed reduce + coalesced store every 64 steps.

#define FOR64(X) \
    X(0) X(1) X(2) X(3) X(4) X(5) X(6) X(7) \
    X(8) X(9) X(10) X(11) X(12) X(13) X(14) X(15) \
    X(16) X(17) X(18) X(19) X(20) X(21) X(22) X(23) \
    X(24) X(25) X(26) X(27) X(28) X(29) X(30) X(31) \
    X(32) X(33) X(34) X(35) X(36) X(37) X(38) X(39) \
    X(40) X(41) X(42) X(43) X(44) X(45) X(46) X(47) \
    X(48) X(49) X(50) X(51) X(52) X(53) X(54) X(55) \
    X(56) X(57) X(58) X(59) X(60) X(61) X(62) X(63)

__global__ __launch_bounds__(64, 1)
void lstm_fused(const float* __restrict__ x,      // [B, T, 4]
                const float* __restrict__ W_ih,   // [256, 4]
                const float* __restrict__ W_hh,   // [256, 64]
                const float* __restrict__ b_ih,   // [256]
                const float* __restrict__ b_hh,   // [256]
                const float* __restrict__ W_fc,   // [1, 64]
                const float* __restrict__ b_fc,   // [1]
                float* __restrict__ out)          // [B, T]
{
    const int b = blockIdx.x;
    const int g = threadIdx.x;   // hidden unit 0..63

    __shared__ float p_s[64][65];   // FC partials ring, stride 65: bank-free

    // ---- one-time: load + pre-scale this lane's 4 gate rows ----
    const float* wr_i = W_hh + (0 * HN + g) * HN;
    const float* wr_f = W_hh + (1 * HN + g) * HN;
    const float* wr_g = W_hh + (2 * HN + g) * HN;
    const float* wr_o = W_hh + (3 * HN + g) * HN;

#define DECL(j) float wi##j, wf##j, wg##j, wo##j;
    FOR64(DECL)
#undef DECL

#define LOAD(j) \
    wi##j = wr_i[j] * LOG2E; \
    wf##j = wr_f[j] * LOG2E; \
    wg##j = wr_g[j] * (2.0f * LOG2E); \
    wo##j = wr_o[j] * LOG2E; \
    asm volatile("" : "+v"(wi##j), "+v"(wf##j), "+v"(wg##j), "+v"(wo##j));
    FOR64(LOAD)
#undef LOAD

    float4 wih_i = *(const float4*)(W_ih + (0 * HN + g) * 4);
    float4 wih_f = *(const float4*)(W_ih + (1 * HN + g) * 4);
    float4 wih_g = *(const float4*)(W_ih + (2 * HN + g) * 4);
    float4 wih_o = *(const float4*)(W_ih + (3 * HN + g) * 4);
    wih_i.x *= LOG2E; wih_i.y *= LOG2E; wih_i.z *= LOG2E; wih_i.w *= LOG2E;
    wih_f.x *= LOG2E; wih_f.y *= LOG2E; wih_f.z *= LOG2E; wih_f.w *= LOG2E;
    wih_g.x *= 2.0f * LOG2E; wih_g.y *= 2.0f * LOG2E;
    wih_g.z *= 2.0f * LOG2E; wih_g.w *= 2.0f * LOG2E;
    wih_o.x *= LOG2E; wih_o.y *= LOG2E; wih_o.z *= LOG2E; wih_o.w *= LOG2E;

    const float bias_i = (b_ih[0 * HN + g] + b_hh[0 * HN + g]) * LOG2E;
    const float bias_f = (b_ih[1 * HN + g] + b_hh[1 * HN + g]) * LOG2E;
    const float bias_g = (b_ih[2 * HN + g] + b_hh[2 * HN + g]) * (2.0f * LOG2E);
    const float bias_o = (b_ih[3 * HN + g] + b_hh[3 * HN + g]) * LOG2E;
    const float wfc = W_fc[g];
    const float bfc = b_fc[0];

    const float* xb = x   + (size_t)b * TLEN * 4;
    float*       ob = out + (size_t)b * TLEN;

    float h = 0.0f, c = 0.0f;
    float4 xt = *(const float4*)(xb);   // software-pipelined x load

    for (int t = 0; t < TLEN; ++t) {
        int tn = t + 1; if (tn >= TLEN) tn = TLEN - 1;
        float4 xnext = *(const float4*)(xb + (size_t)tn * 4);

        // ---- gate pre-activations (pre-scaled units) ----
        float ai = bias_i + wih_i.x * xt.x + wih_i.y * xt.y
                          + wih_i.z * xt.z + wih_i.w * xt.w;
        float af = bias_f + wih_f.x * xt.x + wih_f.y * xt.y
                          + wih_f.z * xt.z + wih_f.w * xt.w;
        float ag = bias_g + wih_g.x * xt.x + wih_g.y * xt.y
                          + wih_g.z * xt.z + wih_g.w * xt.w;
        float ao = bias_o + wih_o.x * xt.x + wih_o.y * xt.y
                          + wih_o.z * xt.z + wih_o.w * xt.w;

        // matvec: h broadcast via readlane -> SGPR source of v_fma (1:4)
#define MAC(j) { \
        float hj = __int_as_float( \
            __builtin_amdgcn_readlane(__float_as_int(h), j)); \
        ai += wi##j * hj; \
        af += wf##j * hj; \
        ag += wg##j * hj; \
        ao += wo##j * hj; }
        FOR64(MAC)
#undef MAC

        // sigmoid(a)=rcp(1+2^-a'), tanh(a)=1-2*rcp(1+2^a'') on pre-scaled a
        float si = __builtin_amdgcn_rcpf(1.0f + __builtin_amdgcn_exp2f(-ai));
        float sf = __builtin_amdgcn_rcpf(1.0f + __builtin_amdgcn_exp2f(-af));
        float tg = 1.0f - 2.0f * __builtin_amdgcn_rcpf(
                                     1.0f + __builtin_amdgcn_exp2f(ag));
        float so = __builtin_amdgcn_rcpf(1.0f + __builtin_amdgcn_exp2f(-ao));

        c = sf * c + si * tg;
        float th = 1.0f - 2.0f * __builtin_amdgcn_rcpf(
                       1.0f + __builtin_amdgcn_exp2f(c * (2.0f * LOG2E)));
        h = so * th;

        // FC partial into ring; transposed reduce + store every 64 steps
        p_s[t & 63][g] = h * wfc;
        if ((t & 63) == 63) {
            __syncthreads();   // single-wave barrier: orders ring w->r
            float s0 = 0.f, s1 = 0.f, s2 = 0.f, s3 = 0.f;
#pragma unroll
            for (int k = 0; k < HN; k += 4) {   // stride-65 rows: bank-free
                s0 += p_s[g][k];
                s1 += p_s[g][k + 1];
                s2 += p_s[g][k + 2];
                s3 += p_s[g][k + 3];
            }
            ob[(t - 63) + g] = (s0 + s1) + (s2 + s3) + bfc;
            __syncthreads();
        }
        xt = xnext;
    }
}

extern "C" void kernel_launch(void* const* d_in, const int* in_sizes, int n_in,
                              void* d_out, int out_size, void* d_ws, size_t ws_size,
                              hipStream_t stream) {
    const float* x    = (const float*)d_in[0];
    const float* W_ih = (const float*)d_in[1];
    const float* W_hh = (const float*)d_in[2];
    const float* b_ih = (const float*)d_in[3];
    const float* b_hh = (const float*)d_in[4];
    const float* W_fc = (const float*)d_in[5];
    const float* b_fc = (const float*)d_in[6];
    float* out = (float*)d_out;

    const int B = in_sizes[0] / (TLEN * 4);   // 1024
    lstm_fused<<<dim3(B), dim3(64), 0, stream>>>(
        x, W_ih, W_hh, b_ih, b_hh, W_fc, b_fc, out);
}

// Round 5
// 836.640 us; speedup vs baseline: 1.3194x; 1.1678x over previous
//
#include <hip/hip_runtime.h>

#define TLEN  1024
#define HN    64
#define LOG2E 1.4426950408889634f

// Two waves (128 threads) per batch element; 1024 blocks = 4 blocks/CU =
// 2 waves/SIMD exactly. Lane g of wave w owns hidden unit g's four gate rows
// (torch i,f,g,o) restricted to j in [32w, 32w+32): 128 named weight floats
// per lane (~190 live regs, safely under the 256 addressable-VGPR limit that
// killed R2-R4's 300-float layouts via scratch spill at VGPR=148-152).
// Per step: 4 half-dots via v_readlane broadcast (immediate lane indices,
// wave-uniform branch), float4 partial exchange through double-buffered LDS
// (1 barrier/step; own+other add commutative -> bitwise-identical h in both
// waves), redundant activations/c/h update in both waves. Wave 1 owns
// x.W_ih, the FC ring [64][65] and the coalesced 64-wide store.
// Occupancy pinned: amdgpu_waves_per_eu(2,2) + LDS padded to ~40.4 KB so the
// compiler's occupancy target == real residency (4 blocks/CU), preventing
// the spill heuristic from re-firing.

#define FOR32(X) \
    X(0) X(1) X(2) X(3) X(4) X(5) X(6) X(7) \
    X(8) X(9) X(10) X(11) X(12) X(13) X(14) X(15) \
    X(16) X(17) X(18) X(19) X(20) X(21) X(22) X(23) \
    X(24) X(25) X(26) X(27) X(28) X(29) X(30) X(31)

__global__ __launch_bounds__(128)
__attribute__((amdgpu_waves_per_eu(2, 2)))
void lstm_fused(const float* __restrict__ x,      // [B, T, 4]
                const float* __restrict__ W_ih,   // [256, 4]
                const float* __restrict__ W_hh,   // [256, 64]
                const float* __restrict__ b_ih,   // [256]
                const float* __restrict__ b_hh,   // [256]
                const float* __restrict__ W_fc,   // [1, 64]
                const float* __restrict__ b_fc,   // [1]
                float* __restrict__ out)          // [B, T]
{
    const int b = blockIdx.x;
    const int tid = threadIdx.x;
    const int g = tid & 63;          // hidden unit 0..63
    const int w = tid >> 6;          // wave 0 / wave 1 (j-half)

    __shared__ __align__(16) float4 px[2][2][HN];   // partial exchange, dbuf
    __shared__ float ring[64][65];                  // FC partials (bank-free)
    __shared__ float pad_lds[4928];                 // occupancy pin: ~40.4 KB total

    // keep pad_lds alive (volatile store is never eliminated)
    ((volatile float*)pad_lds)[tid] = 0.0f;

    // ---- one-time: load + pre-scale this lane's 4 half gate rows ----
    const float* wr_i = W_hh + (0 * HN + g) * HN + 32 * w;
    const float* wr_f = W_hh + (1 * HN + g) * HN + 32 * w;
    const float* wr_g = W_hh + (2 * HN + g) * HN + 32 * w;
    const float* wr_o = W_hh + (3 * HN + g) * HN + 32 * w;

#define DECL(j) float wi##j, wf##j, wg##j, wo##j;
    FOR32(DECL)
#undef DECL

#define LOADW(j) \
    wi##j = wr_i[j] * LOG2E; \
    wf##j = wr_f[j] * LOG2E; \
    wg##j = wr_g[j] * (2.0f * LOG2E); \
    wo##j = wr_o[j] * LOG2E; \
    asm volatile("" : "+v"(wi##j), "+v"(wf##j), "+v"(wg##j), "+v"(wo##j));
    FOR32(LOADW)
#undef LOADW

    // wave 1 extras: x.W_ih (pre-scaled); wave 0 extras: biases (pre-scaled)
    float4 wih_i = {0, 0, 0, 0}, wih_f = {0, 0, 0, 0};
    float4 wih_g = {0, 0, 0, 0}, wih_o = {0, 0, 0, 0};
    float bias_i = 0.f, bias_f = 0.f, bias_g = 0.f, bias_o = 0.f;
    if (w == 1) {
        wih_i = *(const float4*)(W_ih + (0 * HN + g) * 4);
        wih_f = *(const float4*)(W_ih + (1 * HN + g) * 4);
        wih_g = *(const float4*)(W_ih + (2 * HN + g) * 4);
        wih_o = *(const float4*)(W_ih + (3 * HN + g) * 4);
        wih_i.x *= LOG2E; wih_i.y *= LOG2E; wih_i.z *= LOG2E; wih_i.w *= LOG2E;
        wih_f.x *= LOG2E; wih_f.y *= LOG2E; wih_f.z *= LOG2E; wih_f.w *= LOG2E;
        wih_g.x *= 2.0f * LOG2E; wih_g.y *= 2.0f * LOG2E;
        wih_g.z *= 2.0f * LOG2E; wih_g.w *= 2.0f * LOG2E;
        wih_o.x *= LOG2E; wih_o.y *= LOG2E; wih_o.z *= LOG2E; wih_o.w *= LOG2E;
    } else {
        bias_i = (b_ih[0 * HN + g] + b_hh[0 * HN + g]) * LOG2E;
        bias_f = (b_ih[1 * HN + g] + b_hh[1 * HN + g]) * LOG2E;
        bias_g = (b_ih[2 * HN + g] + b_hh[2 * HN + g]) * (2.0f * LOG2E);
        bias_o = (b_ih[3 * HN + g] + b_hh[3 * HN + g]) * LOG2E;
    }
    const float wfc = W_fc[g];
    const float bfc = b_fc[0];

    const float* xb = x   + (size_t)b * TLEN * 4;
    float*       ob = out + (size_t)b * TLEN;

    float h = 0.0f, c = 0.0f;
    float4 xt = {0, 0, 0, 0};
    if (w == 1) xt = *(const float4*)(xb);

    for (int t = 0; t < TLEN; ++t) {
        // ---- half matvec: 32 readlane-broadcast MACs per gate ----
        float pi, pf, pg, po;
#define MACA(j) { \
        float hj = __int_as_float( \
            __builtin_amdgcn_readlane(__float_as_int(h), j)); \
        pi += wi##j * hj; pf += wf##j * hj; \
        pg += wg##j * hj; po += wo##j * hj; }
#define MACB(j) { \
        float hj = __int_as_float( \
            __builtin_amdgcn_readlane(__float_as_int(h), (j) + 32)); \
        pi += wi##j * hj; pf += wf##j * hj; \
        pg += wg##j * hj; po += wo##j * hj; }
        if (w == 0) {
            pi = bias_i; pf = bias_f; pg = bias_g; po = bias_o;
            FOR32(MACA)
        } else {
            int tn = t + 1; if (tn >= TLEN) tn = TLEN - 1;
            float4 xn = *(const float4*)(xb + (size_t)tn * 4);
            pi = wih_i.x * xt.x + wih_i.y * xt.y + wih_i.z * xt.z + wih_i.w * xt.w;
            pf = wih_f.x * xt.x + wih_f.y * xt.y + wih_f.z * xt.z + wih_f.w * xt.w;
            pg = wih_g.x * xt.x + wih_g.y * xt.y + wih_g.z * xt.z + wih_g.w * xt.w;
            po = wih_o.x * xt.x + wih_o.y * xt.y + wih_o.z * xt.z + wih_o.w * xt.w;
            FOR32(MACB)
            xt = xn;
        }
#undef MACA
#undef MACB

        // ---- exchange partials (double-buffered; 1 barrier/step) ----
        px[t & 1][w][g] = make_float4(pi, pf, pg, po);
        __syncthreads();
        float4 oth = px[t & 1][1 - w][g];
        float ai = pi + oth.x;   // commutative -> identical in both waves
        float af = pf + oth.y;
        float ag = pg + oth.z;
        float ao = po + oth.w;

        // ---- activations (pre-scaled): sigmoid / tanh via exp2+rcp ----
        float si = __builtin_amdgcn_rcpf(1.0f + __builtin_amdgcn_exp2f(-ai));
        float sf = __builtin_amdgcn_rcpf(1.0f + __builtin_amdgcn_exp2f(-af));
        float tg = 1.0f - 2.0f * __builtin_amdgcn_rcpf(
                                     1.0f + __builtin_amdgcn_exp2f(ag));
        float so = __builtin_amdgcn_rcpf(1.0f + __builtin_amdgcn_exp2f(-ao));

        c = sf * c + si * tg;
        float th = 1.0f - 2.0f * __builtin_amdgcn_rcpf(
                       1.0f + __builtin_amdgcn_exp2f(c * (2.0f * LOG2E)));
        h = so * th;

        // ---- FC ring + periodic coalesced store (wave 1 only) ----
        if (w == 1) {
            ring[t & 63][g] = h * wfc;
            if ((t & 63) == 63) {
                float s0 = 0.f, s1 = 0.f, s2 = 0.f, s3 = 0.f;
#pragma unroll
                for (int k = 0; k < HN; k += 4) {   // stride-65 rows: 2-way max
                    s0 += ring[g][k];
                    s1 += ring[g][k + 1];
                    s2 += ring[g][k + 2];
                    s3 += ring[g][k + 3];
                }
                ob[(t - 63) + g] = (s0 + s1) + (s2 + s3) + bfc;
            }
        }
    }
}

extern "C" void kernel_launch(void* const* d_in, const int* in_sizes, int n_in,
                              void* d_out, int out_size, void* d_ws, size_t ws_size,
                              hipStream_t stream) {
    const float* x    = (const float*)d_in[0];
    const float* W_ih = (const float*)d_in[1];
    const float* W_hh = (const float*)d_in[2];
    const float* b_ih = (const float*)d_in[3];
    const float* b_hh = (const float*)d_in[4];
    const float* W_fc = (const float*)d_in[5];
    const float* b_fc = (const float*)d_in[6];
    float* out = (float*)d_out;

    const int B = in_sizes[0] / (TLEN * 4);   // 1024
    lstm_fused<<<dim3(B), dim3(128), 0, stream>>>(
        x, W_ih, W_hh, b_ih, b_hh, W_fc, b_fc, out);
}